// Round 4
// baseline (1337.427 us; speedup 1.0000x reference)
//
#include <hip/hip_runtime.h>
#include <hip/hip_bf16.h>
#include <stdint.h>

typedef __attribute__((ext_vector_type(8))) short short8;
typedef __attribute__((ext_vector_type(4))) float floatx4;
using bf16_t = __hip_bfloat16;

#define K_DIM 4096
#define N_DIM 11008
#define NQ_DIM 1376
#define BK 32
#define NSTEPS 128

__device__ __forceinline__ uint32_t pack_bf16x2(float lo, float hi) {
    union { __hip_bfloat162 h2; uint32_t u; } cv;
    cv.h2 = __hip_bfloat162(__float2bfloat16(lo), __float2bfloat16(hi));
    return cv.u;
}

__global__ __launch_bounds__(256, 2)
void awq_gemm(const float* __restrict__ x,
              const int* __restrict__ qweight,
              const int* __restrict__ qzeros,
              const float* __restrict__ scales,
              const float* __restrict__ bias,
              float* __restrict__ out)
{
    __shared__ char lds[16384] __attribute__((aligned(128)));
    // bytes [0,8192):   A tile  [kb=4][row=128][8 k] bf16, addr = kb*2048 + row*16
    // bytes [8192,16K): B tile  16B blocks, blk = kb*128 + n, swizzled blk ^= (blk>>3)&7

    const int tid  = threadIdx.x;
    const int lane = tid & 63;
    const int wid  = tid >> 6;

    const int n0 = blockIdx.x * 128;
    const int m0 = blockIdx.y * 128;

    // ---- A staging: f32 global -> bf16 LDS ----
    // p-th step: f = tid + p*256 in [0,1024): row = f>>3, sub = f&7
    //   loads float4 x[m0+row][k0 + sub*4 .. +3]; writes 8B at kb*2048+row*16+(sub&1)*8
    const int arow_  = tid >> 3;          // rows for p=0 (0..31), +32 per p
    const int asub   = tid & 7;
    const int akb    = asub >> 1;
    const int ahalf  = asub & 1;
    const float* aptr = x + (size_t)(m0 + arow_) * K_DIM + asub * 4;
    const int awr = akb * 2048 + arow_ * 16 + ahalf * 8;

    // ---- B dequant thread mapping: thread owns 2 k-rows x 8 cols ----
    const int nq      = tid & 15;        // local packed column (0..15)
    const int k_local = (tid >> 4) * 2;  // 0..30 even
    const int k8      = k_local & 7;     // even
    const int nq7     = nq & 7;
    const int* qcol = qweight + blockIdx.x * 16 + nq;
    const int* zcol = qzeros  + blockIdx.x * 16 + nq;
    const float* scol = scales + n0 + nq * 8;
    const int bwr_base = 8192 + ((k_local >> 3) * 128 + nq * 8) * 16 + k8 * 2;

    // ---- fragment read offsets (loop-invariant) ----
    const int wm = (wid >> 1) * 64;
    const int wn = (wid & 1) * 64;
    const int aoff = (lane >> 4) * 2048 + (wm + (lane & 15)) * 16;
    int boff[4];
#pragma unroll
    for (int j = 0; j < 4; ++j) {
        int blk = (lane >> 4) * 128 + wn + j * 16 + (lane & 15);
        blk ^= (blk >> 3) & 7;
        boff[j] = 8192 + blk * 16;
    }

    floatx4 acc[4][4];
#pragma unroll
    for (int i = 0; i < 4; ++i)
#pragma unroll
        for (int j = 0; j < 4; ++j)
            acc[i][j] = (floatx4){0.f, 0.f, 0.f, 0.f};

    float s_f[8], mc[8];

    uint32_t q0 = (uint32_t)qcol[(size_t)k_local * NQ_DIM];
    uint32_t q1 = (uint32_t)qcol[(size_t)(k_local + 1) * NQ_DIM];

    for (int ks = 0; ks < NSTEPS; ++ks) {
        const int k0 = ks * BK;

        // ---- A tile: 4 x (float4 load -> cvt -> 8B LDS write) ----
        floatx4 av[4];
#pragma unroll
        for (int p = 0; p < 4; ++p)
            av[p] = *(const floatx4*)(aptr + (size_t)(32 * p) * K_DIM + k0);

        // group-boundary: refresh per-column scale / fused zero term
        if ((ks & 3) == 0) {
            const int g = ks >> 2;
            const uint32_t zw = (uint32_t)zcol[(size_t)g * NQ_DIM];
            const floatx4 sv0 = *(const floatx4*)(scol + (size_t)g * N_DIM);
            const floatx4 sv1 = *(const floatx4*)(scol + (size_t)g * N_DIM + 4);
#pragma unroll
            for (int j = 0; j < 8; ++j) {
                const int sh = ((j & 1) ? 16 : 0) + (j >> 1) * 4;  // AWQ inverse order
                float s = (j < 4) ? sv0[j] : sv1[j - 4];
                float z = (float)((zw >> sh) & 0xFu);
                s_f[j] = s;
                mc[j]  = -(z + 128.0f) * s;
            }
        }

        // prefetch next K-step's qweight words
        uint32_t qn0 = 0, qn1 = 0;
        if (ks + 1 < NSTEPS) {
            qn0 = (uint32_t)qcol[(size_t)(k0 + BK + k_local) * NQ_DIM];
            qn1 = (uint32_t)qcol[(size_t)(k0 + BK + k_local + 1) * NQ_DIM];
        }

        // write A tile (converted) to LDS
#pragma unroll
        for (int p = 0; p < 4; ++p) {
            uint32_t w0 = pack_bf16x2(av[p][0], av[p][1]);
            uint32_t w1 = pack_bf16x2(av[p][2], av[p][3]);
            uint32_t* dst = (uint32_t*)&lds[awr + p * 512];   // 32 rows per p step
            dst[0] = w0;
            dst[1] = w1;
        }

        // dequant current q -> LDS B (8 cols x 2 k per thread)
#pragma unroll
        for (int j = 0; j < 8; ++j) {
            const int sh = ((j & 1) ? 16 : 0) + (j >> 1) * 4;
            uint32_t t0 = (sh <= 16) ? (q0 << (16 - sh)) : (q0 >> (sh - 16));
            uint32_t t1 = (sh <= 16) ? (q1 << (16 - sh)) : (q1 >> (sh - 16));
            // f = 128 + nibble, exactly, via exponent trick
            float f0 = __uint_as_float((t0 & 0x000F0000u) | 0x43000000u);
            float f1 = __uint_as_float((t1 & 0x000F0000u) | 0x43000000u);
            float w0 = fmaf(f0, s_f[j], mc[j]);   // (nib - z) * s
            float w1 = fmaf(f1, s_f[j], mc[j]);
            *(uint32_t*)&lds[bwr_base + ((j ^ nq7) * 16)] = pack_bf16x2(w0, w1);
        }

        __syncthreads();

        short8 af[4], bfr[4];
#pragma unroll
        for (int i = 0; i < 4; ++i) af[i] = *(const short8*)&lds[aoff + i * 256];
#pragma unroll
        for (int j = 0; j < 4; ++j) bfr[j] = *(const short8*)&lds[boff[j]];

#pragma unroll
        for (int i = 0; i < 4; ++i)
#pragma unroll
            for (int j = 0; j < 4; ++j)
                acc[i][j] = __builtin_amdgcn_mfma_f32_16x16x32_bf16(af[i], bfr[j], acc[i][j], 0, 0, 0);

        __syncthreads();
        q0 = qn0; q1 = qn1;
    }

    // ---- epilogue: C/D layout col = lane&15, row = (lane>>4)*4 + r ----
    const int colb = n0 + wn + (lane & 15);
    const int rowb = m0 + wm + ((lane >> 4) << 2);
#pragma unroll
    for (int j = 0; j < 4; ++j) {
        const int col = colb + j * 16;
        const float bias_f = bias[col];
#pragma unroll
        for (int i = 0; i < 4; ++i) {
            const int row = rowb + i * 16;
#pragma unroll
            for (int r = 0; r < 4; ++r) {
                out[(size_t)(row + r) * N_DIM + col] = acc[i][j][r] + bias_f;
            }
        }
    }
}

extern "C" void kernel_launch(void* const* d_in, const int* in_sizes, int n_in,
                              void* d_out, int out_size, void* d_ws, size_t ws_size,
                              hipStream_t stream) {
    const float* x    = (const float*)d_in[0];
    const int* qw     = (const int*)d_in[1];
    const int* qz     = (const int*)d_in[2];
    const float* sc   = (const float*)d_in[3];
    const float* bi   = (const float*)d_in[4];
    float* out        = (float*)d_out;

    const int M = in_sizes[0] / K_DIM;           // 8192
    dim3 grid(N_DIM / 128, M / 128);             // (86, 64)
    awq_gemm<<<grid, 256, 0, stream>>>(x, qw, qz, sc, bi, out);
}